// Round 9
// baseline (249.229 us; speedup 1.0000x reference)
//
#include <hip/hip_runtime.h>
#include <cstdint>
#include <cstddef>

#define B_    4
#define L_    1024
#define DIM_  256
#define DI_   512
#define NTOK  (B_*L_)
#define NC    32
#define CL    (L_/NC)      // 32

__device__ __forceinline__ float siluf_(float x){ return x / (1.0f + __expf(-x)); }
__device__ __forceinline__ float softplusf_(float x){
  return (x > 15.0f) ? x : log1pf(__expf(x));
}

// ---------- verify A_log[d][n] == log(n+1) for all d; flag=1 if structured ----------
__global__ __launch_bounds__(1024) void k_check(const float* __restrict__ A_log,
    int* __restrict__ flag){
  __shared__ int s_ok;
  int tid = threadIdx.x;
  if (tid == 0) s_ok = 1;
  __syncthreads();
  int ok = 1;
  for (int i = tid; i < 512 * 64; i += 1024){
    int n = i & 63;
    float ref = logf((float)(n + 1));
    float v = A_log[i];
    if (fabsf(v - ref) > 1e-5f * fmaxf(1.0f, fabsf(ref))) ok = 0;
  }
  if (!ok) atomicAnd(&s_ok, 0);
  __syncthreads();
  if (tid == 0) *flag = s_ok;
}

// ---------- LN stats: one wave per token ----------
__global__ __launch_bounds__(256) void k_ln_stats(const float* __restrict__ x,
    float* __restrict__ stats){
  int tok  = blockIdx.x * 4 + (threadIdx.x >> 6);
  int lane = threadIdx.x & 63;
  float4 v = *(const float4*)(x + (size_t)tok * DIM_ + lane * 4);
  float s  = v.x + v.y + v.z + v.w;
  float sq = v.x*v.x + v.y*v.y + v.z*v.z + v.w*v.w;
  #pragma unroll
  for (int off = 32; off; off >>= 1){
    s  += __shfl_xor(s,  off, 64);
    sq += __shfl_xor(sq, off, 64);
  }
  if (lane == 0){
    float mu = s * (1.0f / DIM_);
    stats[tok*2]   = mu;
    stats[tok*2+1] = rsqrtf(sq * (1.0f / DIM_) - mu*mu + 1e-5f);
  }
}

// ---------- GEMM1 (LN fused): pad-68 LDS (2-way max), register prefetch ----------
__global__ __launch_bounds__(256) void k_gemm1(const float* __restrict__ x,
    const float* __restrict__ stats, const float* __restrict__ gamma,
    const float* __restrict__ beta, const float* __restrict__ Win,
    float* __restrict__ xz){
  __shared__ float As[16 * 68];
  __shared__ float Bs[16 * 68];
  int tid = threadIdx.x;
  int mBase = blockIdx.y * 64;
  int nBase = blockIdx.x * 64;
  int tx = tid & 15, ty = tid >> 4;
  int am = tid >> 2, ak = (tid & 3) << 2;
  float mu = stats[(mBase+am)*2], rs = stats[(mBase+am)*2+1];
  float acc[4][4] = {};
  const float* xp = x   + (size_t)(mBase+am)*256 + ak;
  const float* wp = Win + (size_t)(nBase+am)*256 + ak;
  float4 av = *(const float4*)(xp);
  float4 bv = *(const float4*)(wp);
  float4 gv = *(const float4*)(gamma + ak);
  float4 be = *(const float4*)(beta  + ak);
  for (int kt = 0; kt < 256; kt += 16){
    As[(ak+0)*68+am] = (av.x - mu) * rs * gv.x + be.x;
    As[(ak+1)*68+am] = (av.y - mu) * rs * gv.y + be.y;
    As[(ak+2)*68+am] = (av.z - mu) * rs * gv.z + be.z;
    As[(ak+3)*68+am] = (av.w - mu) * rs * gv.w + be.w;
    Bs[(ak+0)*68+am]=bv.x; Bs[(ak+1)*68+am]=bv.y;
    Bs[(ak+2)*68+am]=bv.z; Bs[(ak+3)*68+am]=bv.w;
    __syncthreads();
    float4 avN, bvN, gvN, beN;
    if (kt + 16 < 256){
      avN = *(const float4*)(xp + kt + 16);
      bvN = *(const float4*)(wp + kt + 16);
      gvN = *(const float4*)(gamma + kt + 16 + ak);
      beN = *(const float4*)(beta  + kt + 16 + ak);
    }
    #pragma unroll
    for (int kk = 0; kk < 16; kk++){
      float4 a = *(const float4*)&As[kk*68 + ty*4];
      float4 b = *(const float4*)&Bs[kk*68 + tx*4];
      float ar[4] = {a.x,a.y,a.z,a.w}, br[4] = {b.x,b.y,b.z,b.w};
      #pragma unroll
      for (int i=0;i<4;i++)
        #pragma unroll
        for (int j=0;j<4;j++)
          acc[i][j] += ar[i]*br[j];
    }
    __syncthreads();
    av = avN; bv = bvN; gv = gvN; be = beN;
  }
  #pragma unroll
  for (int i=0;i<4;i++){
    float4 o = make_float4(acc[i][0],acc[i][1],acc[i][2],acc[i][3]);
    *(float4*)(xz + (size_t)(mBase+ty*4+i)*1024 + nBase + tx*4) = o;
  }
}

// ---------- causal depthwise conv (w=4) + SiLU ----------
__global__ __launch_bounds__(256) void k_conv(const float* __restrict__ xz,
    const float* __restrict__ cw, const float* __restrict__ cb,
    float* __restrict__ uc){
  int g = blockIdx.x * 256 + threadIdx.x;
  int d = g & 511;
  int tok = g >> 9;
  int t = tok & (L_ - 1);
  float w0 = cw[d*4+0], w1 = cw[d*4+1], w2 = cw[d*4+2], w3 = cw[d*4+3];
  const float* up = xz + (size_t)tok * 1024 + d;
  float acc = cb[d] + w3 * up[0];
  if (t >= 1) acc += w2 * up[-1 * 1024];
  if (t >= 2) acc += w1 * up[-2 * 1024];
  if (t >= 3) acc += w0 * up[-3 * 1024];
  uc[g] = siluf_(acc);
}

// ---------- GEMM2: one output per thread; block = 320 thr; grid 1024 ----------
__global__ __launch_bounds__(320) void k_gemm2(const float* __restrict__ uc,
    const float* __restrict__ Wx, float* __restrict__ dbl){
  __shared__ float As[4 * 516];
  int tid = threadIdx.x;
  int mBase = blockIdx.x * 4;
  for (int idx = tid * 4; idx < 4 * 512; idx += 320 * 4){
    int r = idx >> 9, k = idx & 511;
    *(float4*)&As[r * 516 + k] = *(const float4*)(uc + (size_t)(mBase + r) * 512 + k);
  }
  __syncthreads();
  int n = tid >> 2;
  int r = tid & 3;
  const float* arow = &As[r * 516];
  const float* wp = Wx + (size_t)n * 512;
  float acc = 0.f;
  #pragma unroll 8
  for (int k4 = 0; k4 < 512; k4 += 4){
    float4 a = *(const float4*)&arow[k4];
    float4 w = *(const float4*)(wp + k4);
    acc += a.x*w.x + a.y*w.y + a.z*w.z + a.w*w.w;
  }
  dbl[(size_t)(mBase + r) * 80 + n] = acc;
}

// ---------- dt[m,d] = softplus(dbl[m,:16] . W_dt[d,:] + b_dt[d]) ----------
__global__ __launch_bounds__(256) void k_dt(const float* __restrict__ dbl,
    const float* __restrict__ Wdt, const float* __restrict__ bdt,
    float* __restrict__ dt){
  int g = blockIdx.x * 256 + threadIdx.x;
  int d = g & 511; int m = g >> 9;
  float acc = bdt[d];
  const float* r = dbl + (size_t)m * 80;
  #pragma unroll
  for (int k = 0; k < 16; k++)
    acc += r[k] * Wdt[d * 16 + k];
  dt[g] = softplusf_(acc);
}

// ---------- scan pass A: B staged in LDS; chain-broken dA; branch hoisted ----------
__global__ __launch_bounds__(256, 4) void k_scanA(const float* __restrict__ dt,
    const float* __restrict__ uc, const float* __restrict__ dbl,
    const float* __restrict__ A_log, const int* __restrict__ flagp,
    float* __restrict__ hseg, float* __restrict__ S){
  __shared__ float sB[CL][64];
  int tid  = threadIdx.x;
  int gw   = (blockIdx.x * 256 + tid) >> 6;
  int lane = tid & 63;
  int dsub = lane & 7, ngrp = lane >> 3;
  int grp = gw & 255;
  int c   = gw >> 8;
  int ch  = grp * 8 + dsub;
  int b = ch >> 9, d = ch & 511;
  int tbeg = c * CL;
  {
    const float* Bsrc = dbl + (size_t)b * L_ * 80 + (size_t)tbeg * 80 + 16;
    for (int i = tid; i < CL * 16; i += 256){
      int row = i >> 4, col = (i & 15) << 2;
      *(float4*)&sB[row][col] = *(const float4*)(Bsrc + row * 80 + col);
    }
  }
  __syncthreads();
  int fast = *flagp;
  const float* dtp = dt + (size_t)b * L_ * 512 + d;
  const float* ucp = uc + (size_t)b * L_ * 512 + d;
  float h[8] = {};
  float Ssum = 0.f;
  float st1 = (float)(ngrp * 8 + 1);
  float dtC[4], uC[4];
  #pragma unroll
  for (int j = 0; j < 4; j++){
    dtC[j] = dtp[(size_t)(tbeg+j) * 512];
    uC[j]  = ucp[(size_t)(tbeg+j) * 512];
  }
  if (fast){
    for (int t0 = tbeg; t0 < tbeg + CL; t0 += 4){
      float dtN[4], uN[4];
      if (t0 + 4 < tbeg + CL){
        #pragma unroll
        for (int j = 0; j < 4; j++){
          dtN[j] = dtp[(size_t)(t0+4+j) * 512];
          uN[j]  = ucp[(size_t)(t0+4+j) * 512];
        }
      }
      int tt = t0 - tbeg;
      #pragma unroll
      for (int j = 0; j < 4; j++){
        float4 b0 = *(const float4*)&sB[tt+j][ngrp*8];
        float4 b1 = *(const float4*)&sB[tt+j][ngrp*8+4];
        float sc = dtC[j] * uC[j];
        Ssum += dtC[j];
        float e1 = __expf(-dtC[j]);
        float e2 = e1 * e1;
        float e4 = e2 * e2;
        float dA0 = __expf(-dtC[j] * st1);
        float dA1 = dA0 * e1;
        float dA2 = dA0 * e2;
        float dA3 = dA1 * e2;
        h[0] = dA0 * h[0] + sc * b0.x;
        h[1] = dA1 * h[1] + sc * b0.y;
        h[2] = dA2 * h[2] + sc * b0.z;
        h[3] = dA3 * h[3] + sc * b0.w;
        dA0 *= e4; dA1 *= e4; dA2 *= e4; dA3 *= e4;
        h[4] = dA0 * h[4] + sc * b1.x;
        h[5] = dA1 * h[5] + sc * b1.y;
        h[6] = dA2 * h[6] + sc * b1.z;
        h[7] = dA3 * h[7] + sc * b1.w;
      }
      #pragma unroll
      for (int j = 0; j < 4; j++){ dtC[j] = dtN[j]; uC[j] = uN[j]; }
    }
  } else {
    float Aa[8];
    float4 a0 = *(const float4*)(A_log + (size_t)d*64 + ngrp*8);
    float4 a1 = *(const float4*)(A_log + (size_t)d*64 + ngrp*8 + 4);
    Aa[0]=-__expf(a0.x); Aa[1]=-__expf(a0.y); Aa[2]=-__expf(a0.z); Aa[3]=-__expf(a0.w);
    Aa[4]=-__expf(a1.x); Aa[5]=-__expf(a1.y); Aa[6]=-__expf(a1.z); Aa[7]=-__expf(a1.w);
    for (int t0 = tbeg; t0 < tbeg + CL; t0 += 4){
      float dtN[4], uN[4];
      if (t0 + 4 < tbeg + CL){
        #pragma unroll
        for (int j = 0; j < 4; j++){
          dtN[j] = dtp[(size_t)(t0+4+j) * 512];
          uN[j]  = ucp[(size_t)(t0+4+j) * 512];
        }
      }
      int tt = t0 - tbeg;
      #pragma unroll
      for (int j = 0; j < 4; j++){
        float4 b0 = *(const float4*)&sB[tt+j][ngrp*8];
        float4 b1 = *(const float4*)&sB[tt+j][ngrp*8+4];
        float Bv[8] = {b0.x,b0.y,b0.z,b0.w,b1.x,b1.y,b1.z,b1.w};
        float sc = dtC[j] * uC[j];
        Ssum += dtC[j];
        #pragma unroll
        for (int i = 0; i < 8; i++)
          h[i] = __expf(dtC[j] * Aa[i]) * h[i] + sc * Bv[i];
      }
      #pragma unroll
      for (int j = 0; j < 4; j++){ dtC[j] = dtN[j]; uC[j] = uN[j]; }
    }
  }
  float* hp = hseg + ((size_t)(c * 2048 + ch)) * 64 + ngrp*8;
  *(float4*)hp     = make_float4(h[0],h[1],h[2],h[3]);
  *(float4*)(hp+4) = make_float4(h[4],h[5],h[6],h[7]);
  if (ngrp == 0) S[c * 2048 + ch] = Ssum;
}

// ---------- scan pass B: sequential chunk combine, IN-PLACE ----------
__global__ __launch_bounds__(256) void k_scanB(float* __restrict__ hseg,
    const float* __restrict__ S, const float* __restrict__ A_log,
    const int* __restrict__ flagp){
  int ch   = (blockIdx.x * 256 + threadIdx.x) >> 6;
  int lane = threadIdx.x & 63;
  int d = ch & 511;
  int fast = *flagp;
  float A = fast ? -(float)(lane + 1) : -__expf(A_log[(size_t)d * 64 + lane]);
  float hc = 0.f;
  #pragma unroll 8
  for (int c = 0; c < NC; c++){
    size_t idx = ((size_t)(c * 2048 + ch)) * 64 + lane;
    float hf = hseg[idx];
    hseg[idx] = hc;
    float Sv = S[c * 2048 + ch];
    hc = hf + __expf(A * Sv) * hc;
  }
}

// ---------- scan pass C: B,C,z staged; chain-broken dA; 4-way y partials ----------
__global__ __launch_bounds__(256, 4) void k_scanC(const float* __restrict__ dt,
    const float* __restrict__ uc, const float* __restrict__ dbl,
    const float* __restrict__ C_SA, const float* __restrict__ A_log,
    const int* __restrict__ flagp,
    const float* __restrict__ hin, const float* __restrict__ xz,
    const float* __restrict__ Dp, float* __restrict__ ys){
  __shared__ float sB[CL][64];
  __shared__ float sC[CL][64];
  __shared__ float sZ[CL][32];
  int tid  = threadIdx.x;
  int gw   = (blockIdx.x * 256 + tid) >> 6;
  int lane = tid & 63;
  int dsub = lane & 7, ngrp = lane >> 3;
  int grp = gw & 255;
  int c   = gw >> 8;
  int ch  = grp * 8 + dsub;
  int b = ch >> 9, d = ch & 511;
  int tbeg = c * CL;
  int ch0 = ((blockIdx.x * 4) & 255) * 8;
  int d0  = ch0 & 511;
  {
    const float* Bsrc = dbl  + (size_t)b * L_ * 80 + (size_t)tbeg * 80 + 16;
    const float* Csrc = C_SA + (size_t)b * L_ * 64 + (size_t)tbeg * 64;
    for (int i = tid; i < CL * 16; i += 256){
      int row = i >> 4, col = (i & 15) << 2;
      *(float4*)&sB[row][col] = *(const float4*)(Bsrc + row * 80 + col);
      *(float4*)&sC[row][col] = *(const float4*)(Csrc + row * 64 + col);
    }
    const float* Zsrc = xz + (size_t)b * L_ * 1024 + (size_t)tbeg * 1024 + 512 + d0;
    int zr = tid >> 3, zc = (tid & 7) << 2;
    *(float4*)&sZ[zr][zc] = *(const float4*)(Zsrc + zr * 1024 + zc);
  }
  __syncthreads();
  int fast = *flagp;
  const float* dtp = dt + (size_t)b * L_ * 512 + d;
  const float* ucp = uc + (size_t)b * L_ * 512 + d;
  float Dv = Dp[d];
  int zcol = (grp & 3) * 8 + dsub;
  float*       yw  = ys + (size_t)b * L_ * 512 + d;
  float h[8];
  {
    const float* hp = hin + ((size_t)(c * 2048 + ch)) * 64 + ngrp*8;
    float4 h0 = *(const float4*)hp;
    float4 h1 = *(const float4*)(hp + 4);
    h[0]=h0.x; h[1]=h0.y; h[2]=h0.z; h[3]=h0.w;
    h[4]=h1.x; h[5]=h1.y; h[6]=h1.z; h[7]=h1.w;
  }
  float st1 = (float)(ngrp * 8 + 1);
  float dtC[4], uC[4];
  #pragma unroll
  for (int j = 0; j < 4; j++){
    dtC[j] = dtp[(size_t)(tbeg+j) * 512];
    uC[j]  = ucp[(size_t)(tbeg+j) * 512];
  }
  if (fast){
    for (int t0 = tbeg; t0 < tbeg + CL; t0 += 4){
      float dtN[4], uN[4];
      if (t0 + 4 < tbeg + CL){
        #pragma unroll
        for (int j = 0; j < 4; j++){
          dtN[j] = dtp[(size_t)(t0+4+j) * 512];
          uN[j]  = ucp[(size_t)(t0+4+j) * 512];
        }
      }
      int tt = t0 - tbeg;
      float yp[4];
      #pragma unroll
      for (int j = 0; j < 4; j++){
        float4 b0 = *(const float4*)&sB[tt+j][ngrp*8];
        float4 b1 = *(const float4*)&sB[tt+j][ngrp*8+4];
        float4 c0 = *(const float4*)&sC[tt+j][ngrp*8];
        float4 c1 = *(const float4*)&sC[tt+j][ngrp*8+4];
        float sc = dtC[j] * uC[j];
        float e1 = __expf(-dtC[j]);
        float e2 = e1 * e1;
        float e4 = e2 * e2;
        float dA0 = __expf(-dtC[j] * st1);
        float dA1 = dA0 * e1;
        float dA2 = dA0 * e2;
        float dA3 = dA1 * e2;
        h[0] = dA0 * h[0] + sc * b0.x;
        h[1] = dA1 * h[1] + sc * b0.y;
        h[2] = dA2 * h[2] + sc * b0.z;
        h[3] = dA3 * h[3] + sc * b0.w;
        float y0 = h[0] * c0.x;
        float y1 = h[1] * c0.y;
        float y2 = h[2] * c0.z;
        float y3 = h[3] * c0.w;
        dA0 *= e4; dA1 *= e4; dA2 *= e4; dA3 *= e4;
        h[4] = dA0 * h[4] + sc * b1.x;
        h[5] = dA1 * h[5] + sc * b1.y;
        h[6] = dA2 * h[6] + sc * b1.z;
        h[7] = dA3 * h[7] + sc * b1.w;
        y0 += h[4] * c1.x;
        y1 += h[5] * c1.y;
        y2 += h[6] * c1.z;
        y3 += h[7] * c1.w;
        yp[j] = (y0 + y1) + (y2 + y3);
      }
      #pragma unroll
      for (int off = 8; off < 64; off <<= 1){
        #pragma unroll
        for (int j = 0; j < 4; j++)
          yp[j] += __shfl_xor(yp[j], off, 64);
      }
      if (ngrp == 0){
        #pragma unroll
        for (int j = 0; j < 4; j++){
          float z = sZ[tt+j][zcol];
          yw[(size_t)(t0+j) * 512] = (yp[j] + uC[j] * Dv) * siluf_(z);
        }
      }
      #pragma unroll
      for (int j = 0; j < 4; j++){ dtC[j] = dtN[j]; uC[j] = uN[j]; }
    }
  } else {
    float Aa[8];
    float4 a0 = *(const float4*)(A_log + (size_t)d*64 + ngrp*8);
    float4 a1 = *(const float4*)(A_log + (size_t)d*64 + ngrp*8 + 4);
    Aa[0]=-__expf(a0.x); Aa[1]=-__expf(a0.y); Aa[2]=-__expf(a0.z); Aa[3]=-__expf(a0.w);
    Aa[4]=-__expf(a1.x); Aa[5]=-__expf(a1.y); Aa[6]=-__expf(a1.z); Aa[7]=-__expf(a1.w);
    for (int t0 = tbeg; t0 < tbeg + CL; t0 += 4){
      float dtN[4], uN[4];
      if (t0 + 4 < tbeg + CL){
        #pragma unroll
        for (int j = 0; j < 4; j++){
          dtN[j] = dtp[(size_t)(t0+4+j) * 512];
          uN[j]  = ucp[(size_t)(t0+4+j) * 512];
        }
      }
      int tt = t0 - tbeg;
      float yp[4];
      #pragma unroll
      for (int j = 0; j < 4; j++){
        float4 b0 = *(const float4*)&sB[tt+j][ngrp*8];
        float4 b1 = *(const float4*)&sB[tt+j][ngrp*8+4];
        float4 c0 = *(const float4*)&sC[tt+j][ngrp*8];
        float4 c1 = *(const float4*)&sC[tt+j][ngrp*8+4];
        float sc = dtC[j] * uC[j];
        h[0] = __expf(dtC[j] * Aa[0]) * h[0] + sc * b0.x;
        h[1] = __expf(dtC[j] * Aa[1]) * h[1] + sc * b0.y;
        h[2] = __expf(dtC[j] * Aa[2]) * h[2] + sc * b0.z;
        h[3] = __expf(dtC[j] * Aa[3]) * h[3] + sc * b0.w;
        float y0 = h[0] * c0.x;
        float y1 = h[1] * c0.y;
        float y2 = h[2] * c0.z;
        float y3 = h[3] * c0.w;
        h[4] = __expf(dtC[j] * Aa[4]) * h[4] + sc * b1.x;
        h[5] = __expf(dtC[j] * Aa[5]) * h[5] + sc * b1.y;
        h[6] = __expf(dtC[j] * Aa[6]) * h[6] + sc * b1.z;
        h[7] = __expf(dtC[j] * Aa[7]) * h[7] + sc * b1.w;
        y0 += h[4] * c1.x;
        y1 += h[5] * c1.y;
        y2 += h[6] * c1.z;
        y3 += h[7] * c1.w;
        yp[j] = (y0 + y1) + (y2 + y3);
      }
      #pragma unroll
      for (int off = 8; off < 64; off <<= 1){
        #pragma unroll
        for (int j = 0; j < 4; j++)
          yp[j] += __shfl_xor(yp[j], off, 64);
      }
      if (ngrp == 0){
        #pragma unroll
        for (int j = 0; j < 4; j++){
          float z = sZ[tt+j][zcol];
          yw[(size_t)(t0+j) * 512] = (yp[j] + uC[j] * Dv) * siluf_(z);
        }
      }
      #pragma unroll
      for (int j = 0; j < 4; j++){ dtC[j] = dtN[j]; uC[j] = uN[j]; }
    }
  }
}

// ---------- GEMM3 split-K: pad-68 LDS, register prefetch ----------
__global__ __launch_bounds__(256) void k_gemm3s(const float* __restrict__ Ag,
    const float* __restrict__ Wout, float* __restrict__ pbuf){
  __shared__ float As[16 * 68];
  __shared__ float Bs[16 * 68];
  int tid = threadIdx.x;
  int nBase = blockIdx.x * 64;
  int mBase = blockIdx.y * 64;
  int kBase = blockIdx.z * 128;
  int tx = tid & 15, ty = tid >> 4;
  int am = tid >> 2, ak = (tid & 3) << 2;
  float acc[4][4] = {};
  const float* ap = Ag   + (size_t)(mBase+am)*512 + ak;
  const float* wp = Wout + (size_t)(nBase+am)*512 + ak;
  float4 av = *(const float4*)(ap + kBase);
  float4 bv = *(const float4*)(wp + kBase);
  for (int kt = kBase; kt < kBase + 128; kt += 16){
    As[(ak+0)*68+am]=av.x; As[(ak+1)*68+am]=av.y;
    As[(ak+2)*68+am]=av.z; As[(ak+3)*68+am]=av.w;
    Bs[(ak+0)*68+am]=bv.x; Bs[(ak+1)*68+am]=bv.y;
    Bs[(ak+2)*68+am]=bv.z; Bs[(ak+3)*68+am]=bv.w;
    __syncthreads();
    float4 avN, bvN;
    if (kt + 16 < kBase + 128){
      avN = *(const float4*)(ap + kt + 16);
      bvN = *(const float4*)(wp + kt + 16);
    }
    #pragma unroll
    for (int kk = 0; kk < 16; kk++){
      float4 a = *(const float4*)&As[kk*68 + ty*4];
      float4 b = *(const float4*)&Bs[kk*68 + tx*4];
      float ar[4] = {a.x,a.y,a.z,a.w}, br[4] = {b.x,b.y,b.z,b.w};
      #pragma unroll
      for (int i=0;i<4;i++)
        #pragma unroll
        for (int j=0;j<4;j++)
          acc[i][j] += ar[i]*br[j];
    }
    __syncthreads();
    av = avN; bv = bvN;
  }
  float* pw = pbuf + (size_t)blockIdx.z * (NTOK * 256);
  #pragma unroll
  for (int i=0;i<4;i++){
    float4 o = make_float4(acc[i][0],acc[i][1],acc[i][2],acc[i][3]);
    *(float4*)(pw + (size_t)(mBase+ty*4+i)*256 + nBase + tx*4) = o;
  }
}

// ---------- GEMM3 reduce: out = sum_z pbuf[z] ----------
__global__ __launch_bounds__(256) void k_g3red(const float* __restrict__ pbuf,
    float* __restrict__ out){
  int i4 = (blockIdx.x * 256 + threadIdx.x) * 4;
  float4 a = *(const float4*)(pbuf + i4);
  float4 b = *(const float4*)(pbuf + (size_t)NTOK*256   + i4);
  float4 c = *(const float4*)(pbuf + (size_t)NTOK*512   + i4);
  float4 d = *(const float4*)(pbuf + (size_t)NTOK*768   + i4);
  float4 o = make_float4((a.x+b.x)+(c.x+d.x), (a.y+b.y)+(c.y+d.y),
                         (a.z+b.z)+(c.z+d.z), (a.w+b.w)+(c.w+d.w));
  *(float4*)(out + i4) = o;
}

extern "C" void kernel_launch(void* const* d_in, const int* in_sizes, int n_in,
                              void* d_out, int out_size, void* d_ws, size_t ws_size,
                              hipStream_t stream) {
  const float* x      = (const float*)d_in[0];
  const float* C_SA   = (const float*)d_in[1];
  const float* gamma  = (const float*)d_in[2];
  const float* beta   = (const float*)d_in[3];
  const float* W_in   = (const float*)d_in[4];
  const float* conv_w = (const float*)d_in[5];
  const float* conv_b = (const float*)d_in[6];
  const float* W_x    = (const float*)d_in[7];
  const float* W_dt   = (const float*)d_in[8];
  const float* b_dt   = (const float*)d_in[9];
  const float* A_log  = (const float*)d_in[10];
  const float* Dw     = (const float*)d_in[11];
  const float* W_out  = (const float*)d_in[12];
  float* out = (float*)d_out;

  float* ws    = (float*)d_ws;
  float* stats = ws;                        // 8192 used
  int*   flag  = (int*)(ws + 8192);
  float* xz    = ws    + 16384;             // 4194304
  float* uc    = xz    + 4194304;           // 2097152
  float* dbl   = uc    + 2097152;           // 327680
  float* dtb   = dbl   + 327680;            // 2097152
  float* hseg  = dtb   + 2097152;           // NC*131072 = 4194304 (doubles as hin)
  float* S     = hseg  + 4194304;           // 65536
  float* ysb   = S     + 65536;             // 2097152
  float* pbuf  = hseg;                      // hseg dead after scanC; 4*1048576 floats

  k_check<<<1, 1024, 0, stream>>>(A_log, flag);
  k_ln_stats<<<NTOK/4, 256, 0, stream>>>(x, stats);
  k_gemm1<<<dim3(16, 64), 256, 0, stream>>>(x, stats, gamma, beta, W_in, xz);
  k_conv <<<(NTOK*512)/256, 256, 0, stream>>>(xz, conv_w, conv_b, uc);
  k_gemm2<<<1024, 320, 0, stream>>>(uc, W_x, dbl);
  k_dt   <<<(NTOK*512)/256, 256, 0, stream>>>(dbl, W_dt, b_dt, dtb);
  k_scanA<<<NC*64, 256, 0, stream>>>(dtb, uc, dbl, A_log, flag, hseg, S);
  k_scanB<<<512, 256, 0, stream>>>(hseg, S, A_log, flag);
  k_scanC<<<NC*64, 256, 0, stream>>>(dtb, uc, dbl, C_SA, A_log, flag, hseg, xz, Dw, ysb);
  k_gemm3s<<<dim3(4, 64, 4), 256, 0, stream>>>(ysb, W_out, pbuf);
  k_g3red<<<NTOK*256/1024, 256, 0, stream>>>(pbuf, out);
}

// Round 10
// 236.475 us; speedup vs baseline: 1.0539x; 1.0539x over previous
//
#include <hip/hip_runtime.h>
#include <cstdint>
#include <cstddef>

#define B_    4
#define L_    1024
#define DIM_  256
#define DI_   512
#define NTOK  (B_*L_)
#define NC    32
#define CL    (L_/NC)      // 32

__device__ __forceinline__ float siluf_(float x){ return x / (1.0f + __expf(-x)); }
__device__ __forceinline__ float softplusf_(float x){
  return (x > 15.0f) ? x : log1pf(__expf(x));
}

// ---------- verify A_log[d][n] == log(n+1) for all d; flag=1 if structured ----------
__global__ __launch_bounds__(1024) void k_check(const float* __restrict__ A_log,
    int* __restrict__ flag){
  __shared__ int s_ok;
  int tid = threadIdx.x;
  if (tid == 0) s_ok = 1;
  __syncthreads();
  int ok = 1;
  for (int i = tid; i < 512 * 64; i += 1024){
    int n = i & 63;
    float ref = logf((float)(n + 1));
    float v = A_log[i];
    if (fabsf(v - ref) > 1e-5f * fmaxf(1.0f, fabsf(ref))) ok = 0;
  }
  if (!ok) atomicAnd(&s_ok, 0);
  __syncthreads();
  if (tid == 0) *flag = s_ok;
}

// ---------- LN stats: one wave per token ----------
__global__ __launch_bounds__(256) void k_ln_stats(const float* __restrict__ x,
    float* __restrict__ stats){
  int tok  = blockIdx.x * 4 + (threadIdx.x >> 6);
  int lane = threadIdx.x & 63;
  float4 v = *(const float4*)(x + (size_t)tok * DIM_ + lane * 4);
  float s  = v.x + v.y + v.z + v.w;
  float sq = v.x*v.x + v.y*v.y + v.z*v.z + v.w*v.w;
  #pragma unroll
  for (int off = 32; off; off >>= 1){
    s  += __shfl_xor(s,  off, 64);
    sq += __shfl_xor(sq, off, 64);
  }
  if (lane == 0){
    float mu = s * (1.0f / DIM_);
    stats[tok*2]   = mu;
    stats[tok*2+1] = rsqrtf(sq * (1.0f / DIM_) - mu*mu + 1e-5f);
  }
}

// ---------- GEMM1 (LN fused): pad-68 LDS (2-way max), register prefetch ----------
__global__ __launch_bounds__(256) void k_gemm1(const float* __restrict__ x,
    const float* __restrict__ stats, const float* __restrict__ gamma,
    const float* __restrict__ beta, const float* __restrict__ Win,
    float* __restrict__ xz){
  __shared__ float As[16 * 68];
  __shared__ float Bs[16 * 68];
  int tid = threadIdx.x;
  int mBase = blockIdx.y * 64;
  int nBase = blockIdx.x * 64;
  int tx = tid & 15, ty = tid >> 4;
  int am = tid >> 2, ak = (tid & 3) << 2;
  float mu = stats[(mBase+am)*2], rs = stats[(mBase+am)*2+1];
  float acc[4][4] = {};
  const float* xp = x   + (size_t)(mBase+am)*256 + ak;
  const float* wp = Win + (size_t)(nBase+am)*256 + ak;
  float4 av = *(const float4*)(xp);
  float4 bv = *(const float4*)(wp);
  float4 gv = *(const float4*)(gamma + ak);
  float4 be = *(const float4*)(beta  + ak);
  for (int kt = 0; kt < 256; kt += 16){
    As[(ak+0)*68+am] = (av.x - mu) * rs * gv.x + be.x;
    As[(ak+1)*68+am] = (av.y - mu) * rs * gv.y + be.y;
    As[(ak+2)*68+am] = (av.z - mu) * rs * gv.z + be.z;
    As[(ak+3)*68+am] = (av.w - mu) * rs * gv.w + be.w;
    Bs[(ak+0)*68+am]=bv.x; Bs[(ak+1)*68+am]=bv.y;
    Bs[(ak+2)*68+am]=bv.z; Bs[(ak+3)*68+am]=bv.w;
    __syncthreads();
    float4 avN, bvN, gvN, beN;
    if (kt + 16 < 256){
      avN = *(const float4*)(xp + kt + 16);
      bvN = *(const float4*)(wp + kt + 16);
      gvN = *(const float4*)(gamma + kt + 16 + ak);
      beN = *(const float4*)(beta  + kt + 16 + ak);
    }
    #pragma unroll
    for (int kk = 0; kk < 16; kk++){
      float4 a = *(const float4*)&As[kk*68 + ty*4];
      float4 b = *(const float4*)&Bs[kk*68 + tx*4];
      float ar[4] = {a.x,a.y,a.z,a.w}, br[4] = {b.x,b.y,b.z,b.w};
      #pragma unroll
      for (int i=0;i<4;i++)
        #pragma unroll
        for (int j=0;j<4;j++)
          acc[i][j] += ar[i]*br[j];
    }
    __syncthreads();
    av = avN; bv = bvN; gv = gvN; be = beN;
  }
  #pragma unroll
  for (int i=0;i<4;i++){
    float4 o = make_float4(acc[i][0],acc[i][1],acc[i][2],acc[i][3]);
    *(float4*)(xz + (size_t)(mBase+ty*4+i)*1024 + nBase + tx*4) = o;
  }
}

// ---------- causal depthwise conv (w=4) + SiLU ----------
__global__ __launch_bounds__(256) void k_conv(const float* __restrict__ xz,
    const float* __restrict__ cw, const float* __restrict__ cb,
    float* __restrict__ uc){
  int g = blockIdx.x * 256 + threadIdx.x;
  int d = g & 511;
  int tok = g >> 9;
  int t = tok & (L_ - 1);
  float w0 = cw[d*4+0], w1 = cw[d*4+1], w2 = cw[d*4+2], w3 = cw[d*4+3];
  const float* up = xz + (size_t)tok * 1024 + d;
  float acc = cb[d] + w3 * up[0];
  if (t >= 1) acc += w2 * up[-1 * 1024];
  if (t >= 2) acc += w1 * up[-2 * 1024];
  if (t >= 3) acc += w0 * up[-3 * 1024];
  uc[g] = siluf_(acc);
}

// ---------- GEMM2: one output per thread; block = 320 thr; grid 1024 ----------
__global__ __launch_bounds__(320) void k_gemm2(const float* __restrict__ uc,
    const float* __restrict__ Wx, float* __restrict__ dbl){
  __shared__ float As[4 * 516];
  int tid = threadIdx.x;
  int mBase = blockIdx.x * 4;
  for (int idx = tid * 4; idx < 4 * 512; idx += 320 * 4){
    int r = idx >> 9, k = idx & 511;
    *(float4*)&As[r * 516 + k] = *(const float4*)(uc + (size_t)(mBase + r) * 512 + k);
  }
  __syncthreads();
  int n = tid >> 2;
  int r = tid & 3;
  const float* arow = &As[r * 516];
  const float* wp = Wx + (size_t)n * 512;
  float acc = 0.f;
  #pragma unroll 8
  for (int k4 = 0; k4 < 512; k4 += 4){
    float4 a = *(const float4*)&arow[k4];
    float4 w = *(const float4*)(wp + k4);
    acc += a.x*w.x + a.y*w.y + a.z*w.z + a.w*w.w;
  }
  dbl[(size_t)(mBase + r) * 80 + n] = acc;
}

// ---------- dt[m,d] = softplus(dbl[m,:16] . W_dt[d,:] + b_dt[d]) ----------
__global__ __launch_bounds__(256) void k_dt(const float* __restrict__ dbl,
    const float* __restrict__ Wdt, const float* __restrict__ bdt,
    float* __restrict__ dt){
  int g = blockIdx.x * 256 + threadIdx.x;
  int d = g & 511; int m = g >> 9;
  float acc = bdt[d];
  const float* r = dbl + (size_t)m * 80;
  #pragma unroll
  for (int k = 0; k < 16; k++)
    acc += r[k] * Wdt[d * 16 + k];
  dt[g] = softplusf_(acc);
}

// ---------- scan pass A: B,dt,u ALL staged in LDS; zero VMEM in inner loop ----------
__global__ __launch_bounds__(256, 4) void k_scanA(const float* __restrict__ dt,
    const float* __restrict__ uc, const float* __restrict__ dbl,
    const float* __restrict__ A_log, const int* __restrict__ flagp,
    float* __restrict__ hseg, float* __restrict__ S){
  __shared__ float sB[CL][64];
  __shared__ float sDt[CL][32];
  __shared__ float sU[CL][32];
  int tid  = threadIdx.x;
  int gw   = (blockIdx.x * 256 + tid) >> 6;
  int lane = tid & 63;
  int dsub = lane & 7, ngrp = lane >> 3;
  int grp = gw & 255;
  int c   = gw >> 8;
  int ch  = grp * 8 + dsub;
  int b = ch >> 9, d = ch & 511;
  int tbeg = c * CL;
  int ch0 = ((blockIdx.x * 4) & 255) * 8;   // block covers 32 contiguous channels
  int d0  = ch0 & 511;
  {
    const float* Bsrc = dbl + (size_t)b * L_ * 80 + (size_t)tbeg * 80 + 16;
    for (int i = tid; i < CL * 16; i += 256){
      int row = i >> 4, col = (i & 15) << 2;
      *(float4*)&sB[row][col] = *(const float4*)(Bsrc + row * 80 + col);
    }
    const float* Dsrc = dt + (size_t)b * L_ * 512 + (size_t)tbeg * 512 + d0;
    const float* Usrc = uc + (size_t)b * L_ * 512 + (size_t)tbeg * 512 + d0;
    int zr = tid >> 3, zc = (tid & 7) << 2;
    *(float4*)&sDt[zr][zc] = *(const float4*)(Dsrc + zr * 512 + zc);
    *(float4*)&sU[zr][zc]  = *(const float4*)(Usrc + zr * 512 + zc);
  }
  __syncthreads();
  int fast = *flagp;
  int lch = (grp & 3) * 8 + dsub;
  float h[8] = {};
  float Ssum = 0.f;
  float st1 = (float)(ngrp * 8 + 1);
  if (fast){
    for (int tt = 0; tt < CL; tt += 4){
      #pragma unroll
      for (int j = 0; j < 4; j++){
        float dtv = sDt[tt+j][lch];
        float uv  = sU[tt+j][lch];
        float4 b0 = *(const float4*)&sB[tt+j][ngrp*8];
        float4 b1 = *(const float4*)&sB[tt+j][ngrp*8+4];
        float sc = dtv * uv;
        Ssum += dtv;
        float e1 = __expf(-dtv);
        float e2 = e1 * e1;
        float e4 = e2 * e2;
        float dA0 = __expf(-dtv * st1);
        float dA1 = dA0 * e1;
        float dA2 = dA0 * e2;
        float dA3 = dA1 * e2;
        h[0] = dA0 * h[0] + sc * b0.x;
        h[1] = dA1 * h[1] + sc * b0.y;
        h[2] = dA2 * h[2] + sc * b0.z;
        h[3] = dA3 * h[3] + sc * b0.w;
        dA0 *= e4; dA1 *= e4; dA2 *= e4; dA3 *= e4;
        h[4] = dA0 * h[4] + sc * b1.x;
        h[5] = dA1 * h[5] + sc * b1.y;
        h[6] = dA2 * h[6] + sc * b1.z;
        h[7] = dA3 * h[7] + sc * b1.w;
      }
    }
  } else {
    float Aa[8];
    float4 a0 = *(const float4*)(A_log + (size_t)d*64 + ngrp*8);
    float4 a1 = *(const float4*)(A_log + (size_t)d*64 + ngrp*8 + 4);
    Aa[0]=-__expf(a0.x); Aa[1]=-__expf(a0.y); Aa[2]=-__expf(a0.z); Aa[3]=-__expf(a0.w);
    Aa[4]=-__expf(a1.x); Aa[5]=-__expf(a1.y); Aa[6]=-__expf(a1.z); Aa[7]=-__expf(a1.w);
    for (int tt = 0; tt < CL; tt += 4){
      #pragma unroll
      for (int j = 0; j < 4; j++){
        float dtv = sDt[tt+j][lch];
        float uv  = sU[tt+j][lch];
        float4 b0 = *(const float4*)&sB[tt+j][ngrp*8];
        float4 b1 = *(const float4*)&sB[tt+j][ngrp*8+4];
        float Bv[8] = {b0.x,b0.y,b0.z,b0.w,b1.x,b1.y,b1.z,b1.w};
        float sc = dtv * uv;
        Ssum += dtv;
        #pragma unroll
        for (int i = 0; i < 8; i++)
          h[i] = __expf(dtv * Aa[i]) * h[i] + sc * Bv[i];
      }
    }
  }
  float* hp = hseg + ((size_t)(c * 2048 + ch)) * 64 + ngrp*8;
  *(float4*)hp     = make_float4(h[0],h[1],h[2],h[3]);
  *(float4*)(hp+4) = make_float4(h[4],h[5],h[6],h[7]);
  if (ngrp == 0) S[c * 2048 + ch] = Ssum;
}

// ---------- scan pass B: sequential chunk combine, IN-PLACE ----------
__global__ __launch_bounds__(256) void k_scanB(float* __restrict__ hseg,
    const float* __restrict__ S, const float* __restrict__ A_log,
    const int* __restrict__ flagp){
  int ch   = (blockIdx.x * 256 + threadIdx.x) >> 6;
  int lane = threadIdx.x & 63;
  int d = ch & 511;
  int fast = *flagp;
  float A = fast ? -(float)(lane + 1) : -__expf(A_log[(size_t)d * 64 + lane]);
  float hc = 0.f;
  #pragma unroll 8
  for (int c = 0; c < NC; c++){
    size_t idx = ((size_t)(c * 2048 + ch)) * 64 + lane;
    float hf = hseg[idx];
    hseg[idx] = hc;
    float Sv = S[c * 2048 + ch];
    hc = hf + __expf(A * Sv) * hc;
  }
}

// ---------- scan pass C: B,C,z,dt,u ALL staged; zero VMEM reads in inner loop ----------
__global__ __launch_bounds__(256, 4) void k_scanC(const float* __restrict__ dt,
    const float* __restrict__ uc, const float* __restrict__ dbl,
    const float* __restrict__ C_SA, const float* __restrict__ A_log,
    const int* __restrict__ flagp,
    const float* __restrict__ hin, const float* __restrict__ xz,
    const float* __restrict__ Dp, float* __restrict__ ys){
  __shared__ float sB[CL][64];
  __shared__ float sC[CL][64];
  __shared__ float sZ[CL][32];
  __shared__ float sDt[CL][32];
  __shared__ float sU[CL][32];
  int tid  = threadIdx.x;
  int gw   = (blockIdx.x * 256 + tid) >> 6;
  int lane = tid & 63;
  int dsub = lane & 7, ngrp = lane >> 3;
  int grp = gw & 255;
  int c   = gw >> 8;
  int ch  = grp * 8 + dsub;
  int b = ch >> 9, d = ch & 511;
  int tbeg = c * CL;
  int ch0 = ((blockIdx.x * 4) & 255) * 8;
  int d0  = ch0 & 511;
  {
    const float* Bsrc = dbl  + (size_t)b * L_ * 80 + (size_t)tbeg * 80 + 16;
    const float* Csrc = C_SA + (size_t)b * L_ * 64 + (size_t)tbeg * 64;
    for (int i = tid; i < CL * 16; i += 256){
      int row = i >> 4, col = (i & 15) << 2;
      *(float4*)&sB[row][col] = *(const float4*)(Bsrc + row * 80 + col);
      *(float4*)&sC[row][col] = *(const float4*)(Csrc + row * 64 + col);
    }
    const float* Zsrc = xz + (size_t)b * L_ * 1024 + (size_t)tbeg * 1024 + 512 + d0;
    const float* Dsrc = dt + (size_t)b * L_ * 512 + (size_t)tbeg * 512 + d0;
    const float* Usrc = uc + (size_t)b * L_ * 512 + (size_t)tbeg * 512 + d0;
    int zr = tid >> 3, zc = (tid & 7) << 2;
    *(float4*)&sZ[zr][zc]  = *(const float4*)(Zsrc + zr * 1024 + zc);
    *(float4*)&sDt[zr][zc] = *(const float4*)(Dsrc + zr * 512 + zc);
    *(float4*)&sU[zr][zc]  = *(const float4*)(Usrc + zr * 512 + zc);
  }
  __syncthreads();
  int fast = *flagp;
  float Dv = Dp[d];
  int lch = (grp & 3) * 8 + dsub;
  float*       yw  = ys + (size_t)b * L_ * 512 + d;
  float h[8];
  {
    const float* hp = hin + ((size_t)(c * 2048 + ch)) * 64 + ngrp*8;
    float4 h0 = *(const float4*)hp;
    float4 h1 = *(const float4*)(hp + 4);
    h[0]=h0.x; h[1]=h0.y; h[2]=h0.z; h[3]=h0.w;
    h[4]=h1.x; h[5]=h1.y; h[6]=h1.z; h[7]=h1.w;
  }
  float st1 = (float)(ngrp * 8 + 1);
  if (fast){
    for (int tt = 0; tt < CL; tt += 4){
      float yp[4], uj[4];
      #pragma unroll
      for (int j = 0; j < 4; j++){
        float dtv = sDt[tt+j][lch];
        float uv  = sU[tt+j][lch];
        uj[j] = uv;
        float4 b0 = *(const float4*)&sB[tt+j][ngrp*8];
        float4 b1 = *(const float4*)&sB[tt+j][ngrp*8+4];
        float4 c0 = *(const float4*)&sC[tt+j][ngrp*8];
        float4 c1 = *(const float4*)&sC[tt+j][ngrp*8+4];
        float sc = dtv * uv;
        float e1 = __expf(-dtv);
        float e2 = e1 * e1;
        float e4 = e2 * e2;
        float dA0 = __expf(-dtv * st1);
        float dA1 = dA0 * e1;
        float dA2 = dA0 * e2;
        float dA3 = dA1 * e2;
        h[0] = dA0 * h[0] + sc * b0.x;
        h[1] = dA1 * h[1] + sc * b0.y;
        h[2] = dA2 * h[2] + sc * b0.z;
        h[3] = dA3 * h[3] + sc * b0.w;
        float y0 = h[0] * c0.x;
        float y1 = h[1] * c0.y;
        float y2 = h[2] * c0.z;
        float y3 = h[3] * c0.w;
        dA0 *= e4; dA1 *= e4; dA2 *= e4; dA3 *= e4;
        h[4] = dA0 * h[4] + sc * b1.x;
        h[5] = dA1 * h[5] + sc * b1.y;
        h[6] = dA2 * h[6] + sc * b1.z;
        h[7] = dA3 * h[7] + sc * b1.w;
        y0 += h[4] * c1.x;
        y1 += h[5] * c1.y;
        y2 += h[6] * c1.z;
        y3 += h[7] * c1.w;
        yp[j] = (y0 + y1) + (y2 + y3);
      }
      #pragma unroll
      for (int off = 8; off < 64; off <<= 1){
        #pragma unroll
        for (int j = 0; j < 4; j++)
          yp[j] += __shfl_xor(yp[j], off, 64);
      }
      if (ngrp == 0){
        #pragma unroll
        for (int j = 0; j < 4; j++){
          float z = sZ[tt+j][lch];
          yw[(size_t)(tbeg+tt+j) * 512] = (yp[j] + uj[j] * Dv) * siluf_(z);
        }
      }
    }
  } else {
    float Aa[8];
    float4 a0 = *(const float4*)(A_log + (size_t)d*64 + ngrp*8);
    float4 a1 = *(const float4*)(A_log + (size_t)d*64 + ngrp*8 + 4);
    Aa[0]=-__expf(a0.x); Aa[1]=-__expf(a0.y); Aa[2]=-__expf(a0.z); Aa[3]=-__expf(a0.w);
    Aa[4]=-__expf(a1.x); Aa[5]=-__expf(a1.y); Aa[6]=-__expf(a1.z); Aa[7]=-__expf(a1.w);
    for (int tt = 0; tt < CL; tt += 4){
      float yp[4], uj[4];
      #pragma unroll
      for (int j = 0; j < 4; j++){
        float dtv = sDt[tt+j][lch];
        float uv  = sU[tt+j][lch];
        uj[j] = uv;
        float4 b0 = *(const float4*)&sB[tt+j][ngrp*8];
        float4 b1 = *(const float4*)&sB[tt+j][ngrp*8+4];
        float4 c0 = *(const float4*)&sC[tt+j][ngrp*8];
        float4 c1 = *(const float4*)&sC[tt+j][ngrp*8+4];
        float sc = dtv * uv;
        h[0] = __expf(dtv * Aa[0]) * h[0] + sc * b0.x;
        h[1] = __expf(dtv * Aa[1]) * h[1] + sc * b0.y;
        h[2] = __expf(dtv * Aa[2]) * h[2] + sc * b0.z;
        h[3] = __expf(dtv * Aa[3]) * h[3] + sc * b0.w;
        float y0 = h[0] * c0.x;
        float y1 = h[1] * c0.y;
        float y2 = h[2] * c0.z;
        float y3 = h[3] * c0.w;
        h[4] = __expf(dtv * Aa[4]) * h[4] + sc * b1.x;
        h[5] = __expf(dtv * Aa[5]) * h[5] + sc * b1.y;
        h[6] = __expf(dtv * Aa[6]) * h[6] + sc * b1.z;
        h[7] = __expf(dtv * Aa[7]) * h[7] + sc * b1.w;
        y0 += h[4] * c1.x;
        y1 += h[5] * c1.y;
        y2 += h[6] * c1.z;
        y3 += h[7] * c1.w;
        yp[j] = (y0 + y1) + (y2 + y3);
      }
      #pragma unroll
      for (int off = 8; off < 64; off <<= 1){
        #pragma unroll
        for (int j = 0; j < 4; j++)
          yp[j] += __shfl_xor(yp[j], off, 64);
      }
      if (ngrp == 0){
        #pragma unroll
        for (int j = 0; j < 4; j++){
          float z = sZ[tt+j][lch];
          yw[(size_t)(tbeg+tt+j) * 512] = (yp[j] + uj[j] * Dv) * siluf_(z);
        }
      }
    }
  }
}

// ---------- GEMM3 split-K: pad-68 LDS, register prefetch ----------
__global__ __launch_bounds__(256) void k_gemm3s(const float* __restrict__ Ag,
    const float* __restrict__ Wout, float* __restrict__ pbuf){
  __shared__ float As[16 * 68];
  __shared__ float Bs[16 * 68];
  int tid = threadIdx.x;
  int nBase = blockIdx.x * 64;
  int mBase = blockIdx.y * 64;
  int kBase = blockIdx.z * 128;
  int tx = tid & 15, ty = tid >> 4;
  int am = tid >> 2, ak = (tid & 3) << 2;
  float acc[4][4] = {};
  const float* ap = Ag   + (size_t)(mBase+am)*512 + ak;
  const float* wp = Wout + (size_t)(nBase+am)*512 + ak;
  float4 av = *(const float4*)(ap + kBase);
  float4 bv = *(const float4*)(wp + kBase);
  for (int kt = kBase; kt < kBase + 128; kt += 16){
    As[(ak+0)*68+am]=av.x; As[(ak+1)*68+am]=av.y;
    As[(ak+2)*68+am]=av.z; As[(ak+3)*68+am]=av.w;
    Bs[(ak+0)*68+am]=bv.x; Bs[(ak+1)*68+am]=bv.y;
    Bs[(ak+2)*68+am]=bv.z; Bs[(ak+3)*68+am]=bv.w;
    __syncthreads();
    float4 avN, bvN;
    if (kt + 16 < kBase + 128){
      avN = *(const float4*)(ap + kt + 16);
      bvN = *(const float4*)(wp + kt + 16);
    }
    #pragma unroll
    for (int kk = 0; kk < 16; kk++){
      float4 a = *(const float4*)&As[kk*68 + ty*4];
      float4 b = *(const float4*)&Bs[kk*68 + tx*4];
      float ar[4] = {a.x,a.y,a.z,a.w}, br[4] = {b.x,b.y,b.z,b.w};
      #pragma unroll
      for (int i=0;i<4;i++)
        #pragma unroll
        for (int j=0;j<4;j++)
          acc[i][j] += ar[i]*br[j];
    }
    __syncthreads();
    av = avN; bv = bvN;
  }
  float* pw = pbuf + (size_t)blockIdx.z * (NTOK * 256);
  #pragma unroll
  for (int i=0;i<4;i++){
    float4 o = make_float4(acc[i][0],acc[i][1],acc[i][2],acc[i][3]);
    *(float4*)(pw + (size_t)(mBase+ty*4+i)*256 + nBase + tx*4) = o;
  }
}

// ---------- GEMM3 reduce: out = sum_z pbuf[z] ----------
__global__ __launch_bounds__(256) void k_g3red(const float* __restrict__ pbuf,
    float* __restrict__ out){
  int i4 = (blockIdx.x * 256 + threadIdx.x) * 4;
  float4 a = *(const float4*)(pbuf + i4);
  float4 b = *(const float4*)(pbuf + (size_t)NTOK*256   + i4);
  float4 c = *(const float4*)(pbuf + (size_t)NTOK*512   + i4);
  float4 d = *(const float4*)(pbuf + (size_t)NTOK*768   + i4);
  float4 o = make_float4((a.x+b.x)+(c.x+d.x), (a.y+b.y)+(c.y+d.y),
                         (a.z+b.z)+(c.z+d.z), (a.w+b.w)+(c.w+d.w));
  *(float4*)(out + i4) = o;
}

extern "C" void kernel_launch(void* const* d_in, const int* in_sizes, int n_in,
                              void* d_out, int out_size, void* d_ws, size_t ws_size,
                              hipStream_t stream) {
  const float* x      = (const float*)d_in[0];
  const float* C_SA   = (const float*)d_in[1];
  const float* gamma  = (const float*)d_in[2];
  const float* beta   = (const float*)d_in[3];
  const float* W_in   = (const float*)d_in[4];
  const float* conv_w = (const float*)d_in[5];
  const float* conv_b = (const float*)d_in[6];
  const float* W_x    = (const float*)d_in[7];
  const float* W_dt   = (const float*)d_in[8];
  const float* b_dt   = (const float*)d_in[9];
  const float* A_log  = (const float*)d_in[10];
  const float* Dw     = (const float*)d_in[11];
  const float* W_out  = (const float*)d_in[12];
  float* out = (float*)d_out;

  float* ws    = (float*)d_ws;
  float* stats = ws;                        // 8192 used
  int*   flag  = (int*)(ws + 8192);
  float* xz    = ws    + 16384;             // 4194304
  float* uc    = xz    + 4194304;           // 2097152
  float* dbl   = uc    + 2097152;           // 327680
  float* dtb   = dbl   + 327680;            // 2097152
  float* hseg  = dtb   + 2097152;           // NC*131072 = 4194304 (doubles as hin)
  float* S     = hseg  + 4194304;           // 65536
  float* ysb   = S     + 65536;             // 2097152
  float* pbuf  = hseg;                      // hseg dead after scanC; 4*1048576 floats

  k_check<<<1, 1024, 0, stream>>>(A_log, flag);
  k_ln_stats<<<NTOK/4, 256, 0, stream>>>(x, stats);
  k_gemm1<<<dim3(16, 64), 256, 0, stream>>>(x, stats, gamma, beta, W_in, xz);
  k_conv <<<(NTOK*512)/256, 256, 0, stream>>>(xz, conv_w, conv_b, uc);
  k_gemm2<<<1024, 320, 0, stream>>>(uc, W_x, dbl);
  k_dt   <<<(NTOK*512)/256, 256, 0, stream>>>(dbl, W_dt, b_dt, dtb);
  k_scanA<<<NC*64, 256, 0, stream>>>(dtb, uc, dbl, A_log, flag, hseg, S);
  k_scanB<<<512, 256, 0, stream>>>(hseg, S, A_log, flag);
  k_scanC<<<NC*64, 256, 0, stream>>>(dtb, uc, dbl, C_SA, A_log, flag, hseg, xz, Dw, ysb);
  k_gemm3s<<<dim3(4, 64, 4), 256, 0, stream>>>(ysb, W_out, pbuf);
  k_g3red<<<NTOK*256/1024, 256, 0, stream>>>(pbuf, out);
}